// Round 3
// baseline (470.698 us; speedup 1.0000x reference)
//
#include <hip/hip_runtime.h>

#define SS 2048
#define DD 128
#define NB 16
#define TM 64
#define TN 64
#define NITER (SS / TN)
#define PSTRIDE 72

// scale * log2(e): exp2-based softmax (consistent in num+denom == exact softmax)
#define SL2E (0.08838834764831845f * 1.4426950408889634f)

typedef short bf16x8 __attribute__((ext_vector_type(8)));
typedef float f32x4 __attribute__((ext_vector_type(4)));

__device__ __forceinline__ unsigned short f2bf(float x) {
    unsigned u = __builtin_bit_cast(unsigned, x);
    u += 0x7fffu + ((u >> 16) & 1u);          // RNE
    return (unsigned short)(u >> 16);
}

__device__ __forceinline__ float fexp2(float x) {
#if __has_builtin(__builtin_amdgcn_exp2f)
    return __builtin_amdgcn_exp2f(x);
#else
    return __expf(x * 0.6931471805599453f);
#endif
}

// ---- pre-kernel: K fp32->bf16 (x=2,3) and V [B][S][D] -> Vt [B][D][S] bf16 (x=0,1) ----
__global__ void prep_kernel(const float* __restrict__ k, const float* __restrict__ v,
                            unsigned short* __restrict__ kb, unsigned short* __restrict__ vt) {
    __shared__ unsigned short t[64 * 72];
    const int x = blockIdx.x, b = blockIdx.z, sb = blockIdx.y * 64;
    const int tid = threadIdx.x;
    if (x < 2) {
        const int db = x * 64;
        const int r16 = tid >> 4, c4 = (tid & 15) * 4;
        for (int i = 0; i < 4; ++i) {
            int sl = i * 16 + r16;
            float4 xx = *(const float4*)(v + ((size_t)(b * SS + sb + sl) * DD + db + c4));
            ushort4 u; u.x = f2bf(xx.x); u.y = f2bf(xx.y); u.z = f2bf(xx.z); u.w = f2bf(xx.w);
            *(ushort4*)&t[sl * 72 + c4] = u;
        }
        __syncthreads();
        for (int i = 0; i < 4; ++i) {
            int dl = i * 16 + r16;
            ushort4 u;
            u.x = t[(c4 + 0) * 72 + dl];
            u.y = t[(c4 + 1) * 72 + dl];
            u.z = t[(c4 + 2) * 72 + dl];
            u.w = t[(c4 + 3) * 72 + dl];
            *(ushort4*)(vt + ((size_t)(b * DD + db + dl) * SS + sb + c4)) = u;
        }
    } else {
        const int c0 = (x - 2) * 64;
        for (int i = 0; i < 4; ++i) {
            int e = i * 1024 + tid * 4;
            int r = e >> 6, c = e & 63;
            size_t off = (size_t)(b * SS + sb + r) * DD + c0 + c;
            float4 xx = *(const float4*)(k + off);
            ushort4 u; u.x = f2bf(xx.x); u.y = f2bf(xx.y); u.z = f2bf(xx.z); u.w = f2bf(xx.w);
            *(ushort4*)(kb + off) = u;
        }
    }
}

// ---- main fused attention: direct-from-L2 K/V fragments, LDS only for P transpose ----
__global__ __launch_bounds__(512, 4)
void attn_kernel(const float* __restrict__ q,
                 const unsigned short* __restrict__ kb,
                 const unsigned short* __restrict__ vt,
                 float* __restrict__ attn, float* __restrict__ ctx) {
    __shared__ unsigned short P_lds[2][TM * PSTRIDE];   // 2 x 9216 B
    __shared__ float rs_lds[TM];
    __shared__ float inv_lds[TM];

    const int tid = threadIdx.x;
    const int lane = tid & 63, w = tid >> 6;
    const int wm = w >> 2, wn = w & 3;               // 2 row-waves x 4 col-waves
    const int l15 = lane & 15, quad = lane >> 4;

    // XCD-batch swizzle: XCD x (bid%8) handles batches {2x, 2x+1} -> K/V L2-resident
    const int bid = blockIdx.x;
    const int bb = ((bid & 7) << 1) | ((bid >> 3) & 1);
    const int q0 = (bid >> 4) * TM;

    if (tid < TM) rs_lds[tid] = 0.0f;

    // Q fragments from fp32 global, converted in registers. A-layout: m=l15, k=quad*8+j
    bf16x8 qf[2][4];
    {
        const float* qg = q + ((size_t)(bb * SS + q0 + wm * 32 + l15)) * DD + quad * 8;
        for (int mi = 0; mi < 2; ++mi)
            for (int kk = 0; kk < 4; ++kk) {
                float4 a = *(const float4*)(qg + mi * 16 * DD + kk * 32);
                float4 b = *(const float4*)(qg + mi * 16 * DD + kk * 32 + 4);
                bf16x8 f;
                f[0] = (short)f2bf(a.x); f[1] = (short)f2bf(a.y);
                f[2] = (short)f2bf(a.z); f[3] = (short)f2bf(a.w);
                f[4] = (short)f2bf(b.x); f[5] = (short)f2bf(b.y);
                f[6] = (short)f2bf(b.z); f[7] = (short)f2bf(b.w);
                qf[mi][kk] = f;
            }
    }

    // per-lane fragment base pointers (each frag load: full 64B-line utilization)
    const unsigned short* kfb = kb + (size_t)bb * SS * DD + (size_t)(wn * 16 + l15) * DD + quad * 8;
    const unsigned short* vgb = vt + (size_t)bb * DD * SS;

    // ================= phase A: rowsums, zero barriers =================
    float rs[8];
    for (int j = 0; j < 8; ++j) rs[j] = 0.0f;

    for (int it = 0; it < NITER; ++it) {
        const unsigned short* kg = kfb + (size_t)(it * TN) * DD;
        f32x4 acc[2];
        acc[0] = (f32x4){0.f, 0.f, 0.f, 0.f};
        acc[1] = (f32x4){0.f, 0.f, 0.f, 0.f};
        bf16x8 kf[4];
        for (int kk = 0; kk < 4; ++kk) kf[kk] = *(const bf16x8*)(kg + kk * 32);
        for (int kk = 0; kk < 4; ++kk) {
            acc[0] = __builtin_amdgcn_mfma_f32_16x16x32_bf16(qf[0][kk], kf[kk], acc[0], 0, 0, 0);
            acc[1] = __builtin_amdgcn_mfma_f32_16x16x32_bf16(qf[1][kk], kf[kk], acc[1], 0, 0, 0);
        }
        for (int mi = 0; mi < 2; ++mi)
            for (int r = 0; r < 4; ++r)
                rs[mi * 4 + r] += fexp2(acc[mi][r] * SL2E);
    }

    for (int j = 0; j < 8; ++j) {
        float s = rs[j];
        s += __shfl_xor(s, 1, 64);
        s += __shfl_xor(s, 2, 64);
        s += __shfl_xor(s, 4, 64);
        s += __shfl_xor(s, 8, 64);
        rs[j] = s;
    }
    if (l15 == 0)
        for (int mi = 0; mi < 2; ++mi)
            for (int r = 0; r < 4; ++r)
                atomicAdd(&rs_lds[wm * 32 + mi * 16 + quad * 4 + r], rs[mi * 4 + r]);
    __syncthreads();
    if (tid < TM) inv_lds[tid] = 1.0f / rs_lds[tid];
    __syncthreads();
    float inv[8];
    for (int mi = 0; mi < 2; ++mi)
        for (int r = 0; r < 4; ++r)
            inv[mi * 4 + r] = inv_lds[wm * 32 + mi * 16 + quad * 4 + r];

    // ================= phase B: 1 barrier/iter (double-buffered P_lds) =================
    f32x4 cacc[2][2];
    for (int mi = 0; mi < 2; ++mi)
        for (int ni = 0; ni < 2; ++ni) cacc[mi][ni] = (f32x4){0.f, 0.f, 0.f, 0.f};

    float* ap[8];
    for (int mi = 0; mi < 2; ++mi)
        for (int r = 0; r < 4; ++r)
            ap[mi * 4 + r] = attn + (size_t)bb * SS * SS
                           + (size_t)(q0 + wm * 32 + mi * 16 + quad * 4 + r) * SS
                           + wn * 16 + l15;

    // V B-frag base: row index is d = wn*32 + ni*16 + l15, k elems = keys
    const unsigned short* vfb = vgb + (size_t)(wn * 32 + l15) * SS + quad * 8;

    for (int it = 0; it < NITER; ++it) {
        const int k0 = it * TN;

        // V fragments for this key-tile, loaded early (consumed after the barrier)
        bf16x8 vf[2][2];
        for (int ni = 0; ni < 2; ++ni)
            for (int kk = 0; kk < 2; ++kk)
                vf[ni][kk] = *(const bf16x8*)(vfb + (size_t)(ni * 16) * SS + k0 + kk * 32);

        // QK^T for this tile
        const unsigned short* kg = kfb + (size_t)k0 * DD;
        f32x4 acc[2];
        acc[0] = (f32x4){0.f, 0.f, 0.f, 0.f};
        acc[1] = (f32x4){0.f, 0.f, 0.f, 0.f};
        bf16x8 kf[4];
        for (int kk = 0; kk < 4; ++kk) kf[kk] = *(const bf16x8*)(kg + kk * 32);
        for (int kk = 0; kk < 4; ++kk) {
            acc[0] = __builtin_amdgcn_mfma_f32_16x16x32_bf16(qf[0][kk], kf[kk], acc[0], 0, 0, 0);
            acc[1] = __builtin_amdgcn_mfma_f32_16x16x32_bf16(qf[1][kk], kf[kk], acc[1], 0, 0, 0);
        }

        // normalized P: keep fp32 in regs for the global store, bf16 into P_lds buffer
        unsigned short* pb = P_lds[it & 1];
        float pv[8];
        for (int mi = 0; mi < 2; ++mi)
            for (int r = 0; r < 4; ++r) {
                float p = fexp2(acc[mi][r] * SL2E) * inv[mi * 4 + r];
                pv[mi * 4 + r] = p;
                pb[(wm * 32 + mi * 16 + quad * 4 + r) * PSTRIDE + wn * 16 + l15] = f2bf(p);
            }
        __syncthreads();   // P buffer complete; prev-iter readers done with buf^1

        // PV: A-frags from P_lds, B-frags already in registers
        for (int kk = 0; kk < 2; ++kk) {
            bf16x8 af[2];
            for (int mi = 0; mi < 2; ++mi)
                af[mi] = *(const bf16x8*)&pb[(wm * 32 + mi * 16 + l15) * PSTRIDE + kk * 32 + quad * 8];
            for (int ni = 0; ni < 2; ++ni)
                for (int mi = 0; mi < 2; ++mi)
                    cacc[mi][ni] = __builtin_amdgcn_mfma_f32_16x16x32_bf16(af[mi], vf[ni][kk], cacc[mi][ni], 0, 0, 0);
        }

        // attention store (fp32, 4x64B segments per inst), drains by next barrier
        for (int j = 0; j < 8; ++j) {
            ap[j][0] = pv[j];
            ap[j] += TN;
        }
    }

    // epilogue: context
    float* cg = ctx + ((size_t)(bb * SS) + q0) * DD;
    for (int mi = 0; mi < 2; ++mi)
        for (int ni = 0; ni < 2; ++ni)
            for (int r = 0; r < 4; ++r) {
                int row = wm * 32 + mi * 16 + quad * 4 + r;
                int col = wn * 32 + ni * 16 + l15;
                cg[(size_t)row * DD + col] = cacc[mi][ni][r];
            }
}

extern "C" void kernel_launch(void* const* d_in, const int* in_sizes, int n_in,
                              void* d_out, int out_size, void* d_ws, size_t ws_size,
                              hipStream_t stream) {
    const float* q = (const float*)d_in[0];
    const float* k = (const float*)d_in[1];
    const float* v = (const float*)d_in[2];
    float* ctx = (float*)d_out;
    float* attn = ctx + (size_t)NB * SS * DD;

    unsigned short* kb = (unsigned short*)d_ws;            // B*S*D bf16
    unsigned short* vt = kb + (size_t)NB * SS * DD;        // [B][D][S] bf16

    prep_kernel<<<dim3(4, SS / 64, NB), 256, 0, stream>>>(k, v, kb, vt);
    attn_kernel<<<dim3((SS / TM) * NB), 512, 0, stream>>>(q, kb, vt, attn, ctx);
}

// Round 4
// 394.069 us; speedup vs baseline: 1.1945x; 1.1945x over previous
//
#include <hip/hip_runtime.h>

#define SS 2048
#define DD 128
#define NB 16
#define TM 64
#define TN 128
#define NITER (SS / TN)      // 16
#define KSTRIDE 136          // 128 + 8 pad (bf16 elems)
#define PSTRIDE 136          // 128 + 8 pad

// scale * log2(e): exp2-based softmax (consistent num+denom == exact softmax)
#define SL2E (0.08838834764831845f * 1.4426950408889634f)

typedef short bf16x8 __attribute__((ext_vector_type(8)));
typedef float f32x4 __attribute__((ext_vector_type(4)));

__device__ __forceinline__ unsigned short f2bf(float x) {
    unsigned u = __builtin_bit_cast(unsigned, x);
    u += 0x7fffu + ((u >> 16) & 1u);          // RNE
    return (unsigned short)(u >> 16);
}

__device__ __forceinline__ float fexp2(float x) {
#if __has_builtin(__builtin_amdgcn_exp2f)
    return __builtin_amdgcn_exp2f(x);
#else
    return __expf(x * 0.6931471805599453f);
#endif
}

// ---- pre-kernel: K fp32->bf16 (x=2,3) and V [B][S][D] -> Vt [B][D][S] bf16 (x=0,1) ----
__global__ void prep_kernel(const float* __restrict__ k, const float* __restrict__ v,
                            unsigned short* __restrict__ kb, unsigned short* __restrict__ vt) {
    __shared__ unsigned short t[64 * 72];
    const int x = blockIdx.x, b = blockIdx.z, sb = blockIdx.y * 64;
    const int tid = threadIdx.x;
    if (x < 2) {
        const int db = x * 64;
        const int r16 = tid >> 4, c4 = (tid & 15) * 4;
        for (int i = 0; i < 4; ++i) {
            int sl = i * 16 + r16;
            float4 xx = *(const float4*)(v + ((size_t)(b * SS + sb + sl) * DD + db + c4));
            ushort4 u; u.x = f2bf(xx.x); u.y = f2bf(xx.y); u.z = f2bf(xx.z); u.w = f2bf(xx.w);
            *(ushort4*)&t[sl * 72 + c4] = u;
        }
        __syncthreads();
        for (int i = 0; i < 4; ++i) {
            int dl = i * 16 + r16;
            ushort4 u;
            u.x = t[(c4 + 0) * 72 + dl];
            u.y = t[(c4 + 1) * 72 + dl];
            u.z = t[(c4 + 2) * 72 + dl];
            u.w = t[(c4 + 3) * 72 + dl];
            *(ushort4*)(vt + ((size_t)(b * DD + db + dl) * SS + sb + c4)) = u;
        }
    } else {
        const int c0 = (x - 2) * 64;
        for (int i = 0; i < 4; ++i) {
            int e = i * 1024 + tid * 4;
            int r = e >> 6, c = e & 63;
            size_t off = (size_t)(b * SS + sb + r) * DD + c0 + c;
            float4 xx = *(const float4*)(k + off);
            ushort4 u; u.x = f2bf(xx.x); u.y = f2bf(xx.y); u.z = f2bf(xx.z); u.w = f2bf(xx.w);
            *(ushort4*)(kb + off) = u;
        }
    }
}

// ---- main fused attention: LDS-staged K (dbuf phase A), P dbuf, V direct-L2 early ----
__global__ __launch_bounds__(512, 4)
void attn_kernel(const float* __restrict__ q,
                 const unsigned short* __restrict__ kb,
                 const unsigned short* __restrict__ vt,
                 float* __restrict__ attn, float* __restrict__ ctx) {
    // union: phase A = K double buffer; phase B = smem[0]:K tile, smem[1]:P double buffer
    __shared__ unsigned short smem[2][TN * KSTRIDE];   // 2 x 34816 B
    __shared__ float rs_lds[TM];
    __shared__ float inv_lds[TM];

    const int tid = threadIdx.x;
    const int lane = tid & 63, w = tid >> 6;
    const int wm = w >> 2, wn = w & 3;               // 2 row-waves x 4 col-waves
    const int l15 = lane & 15, quad = lane >> 4;

    // XCD-batch swizzle: XCD x (bid%8) handles batches {2x, 2x+1} -> K/V L2-resident
    const int bid = blockIdx.x;
    const int bb = ((bid & 7) << 1) | ((bid >> 3) & 1);
    const int q0 = (bid >> 4) * TM;

    if (tid < TM) rs_lds[tid] = 0.0f;

    // Q fragments from fp32 global, converted in regs. A-layout: m=l15, k=quad*8+j
    bf16x8 qf[2][4];
    {
        const float* qg = q + ((size_t)(bb * SS + q0 + wm * 32 + l15)) * DD + quad * 8;
        for (int mi = 0; mi < 2; ++mi)
            for (int kk = 0; kk < 4; ++kk) {
                float4 a = *(const float4*)(qg + mi * 16 * DD + kk * 32);
                float4 b = *(const float4*)(qg + mi * 16 * DD + kk * 32 + 4);
                bf16x8 f;
                f[0] = (short)f2bf(a.x); f[1] = (short)f2bf(a.y);
                f[2] = (short)f2bf(a.z); f[3] = (short)f2bf(a.w);
                f[4] = (short)f2bf(b.x); f[5] = (short)f2bf(b.y);
                f[6] = (short)f2bf(b.z); f[7] = (short)f2bf(b.w);
                qf[mi][kk] = f;
            }
    }

    const unsigned short* kgb = kb + (size_t)bb * SS * DD;

    // ================= phase A: K dbuf, 1 barrier/iter =================
    // prologue: stage tile 0 -> smem[0]
    for (int c = 0; c < 4; ++c) {
        int e = c * 4096 + tid * 8;
        *(bf16x8*)&smem[0][(e >> 7) * KSTRIDE + (e & 127)] = *(const bf16x8*)(kgb + e);
    }
    __syncthreads();

    float rs[8];
    for (int j = 0; j < 8; ++j) rs[j] = 0.0f;

    for (int it = 0; it < NITER; ++it) {
        bf16x8 g[4];
        if (it + 1 < NITER) {
            const unsigned short* kg = kgb + (size_t)((it + 1) * TN) * DD;
            for (int c = 0; c < 4; ++c)
                g[c] = *(const bf16x8*)(kg + c * 4096 + tid * 8);
        }
        const unsigned short* kt = smem[it & 1];
        f32x4 acc[2][2];
        for (int mi = 0; mi < 2; ++mi)
            for (int nt = 0; nt < 2; ++nt) acc[mi][nt] = (f32x4){0.f, 0.f, 0.f, 0.f};
        for (int nt = 0; nt < 2; ++nt)
            for (int kk = 0; kk < 4; ++kk) {
                bf16x8 kf = *(const bf16x8*)&kt[(wn * 32 + nt * 16 + l15) * KSTRIDE + kk * 32 + quad * 8];
                acc[0][nt] = __builtin_amdgcn_mfma_f32_16x16x32_bf16(qf[0][kk], kf, acc[0][nt], 0, 0, 0);
                acc[1][nt] = __builtin_amdgcn_mfma_f32_16x16x32_bf16(qf[1][kk], kf, acc[1][nt], 0, 0, 0);
            }
        for (int mi = 0; mi < 2; ++mi)
            for (int r = 0; r < 4; ++r)
                rs[mi * 4 + r] += fexp2(acc[mi][0][r] * SL2E) + fexp2(acc[mi][1][r] * SL2E);
        if (it + 1 < NITER) {
            unsigned short* kd = smem[(it + 1) & 1];
            for (int c = 0; c < 4; ++c) {
                int e = c * 4096 + tid * 8;
                *(bf16x8*)&kd[(e >> 7) * KSTRIDE + (e & 127)] = g[c];
            }
        }
        __syncthreads();
    }

    // issue phase-B tile-0 K reload while reducing
    bf16x8 g0[4];
    for (int c = 0; c < 4; ++c)
        g0[c] = *(const bf16x8*)(kgb + c * 4096 + tid * 8);

    for (int j = 0; j < 8; ++j) {
        float s = rs[j];
        s += __shfl_xor(s, 1, 64);
        s += __shfl_xor(s, 2, 64);
        s += __shfl_xor(s, 4, 64);
        s += __shfl_xor(s, 8, 64);
        rs[j] = s;
    }
    if (l15 == 0)
        for (int mi = 0; mi < 2; ++mi)
            for (int r = 0; r < 4; ++r)
                atomicAdd(&rs_lds[wm * 32 + mi * 16 + quad * 4 + r], rs[mi * 4 + r]);
    __syncthreads();
    if (tid < TM) inv_lds[tid] = 1.0f / rs_lds[tid];
    // stage K tile 0 -> smem[0] (phase-A reads all done)
    for (int c = 0; c < 4; ++c) {
        int e = c * 4096 + tid * 8;
        *(bf16x8*)&smem[0][(e >> 7) * KSTRIDE + (e & 127)] = g0[c];
    }
    __syncthreads();
    float inv[8];
    for (int mi = 0; mi < 2; ++mi)
        for (int r = 0; r < 4; ++r)
            inv[mi * 4 + r] = inv_lds[wm * 32 + mi * 16 + quad * 4 + r];

    // ================= phase B: 2 barriers/iter =================
    f32x4 cacc[2][2];
    for (int mi = 0; mi < 2; ++mi)
        for (int ni = 0; ni < 2; ++ni) cacc[mi][ni] = (f32x4){0.f, 0.f, 0.f, 0.f};

    const unsigned short* vfb = vt + (size_t)bb * DD * SS + (size_t)(wn * 32 + l15) * SS + quad * 8;
    float* apb = attn + (size_t)bb * SS * SS + (size_t)(q0 + wm * 32 + quad * 4) * SS + wn * 32 + l15;

    for (int it = 0; it < NITER; ++it) {
        const int k0 = it * TN;

        // early V loads (kk 0,1), consumed after barrier (a)
        bf16x8 vf[2][2];
        for (int ni = 0; ni < 2; ++ni)
            for (int kk = 0; kk < 2; ++kk)
                vf[ni][kk] = *(const bf16x8*)(vfb + ni * 16 * SS + k0 + kk * 32);

        // QK^T from smem[0]
        f32x4 acc[2][2];
        for (int mi = 0; mi < 2; ++mi)
            for (int nt = 0; nt < 2; ++nt) acc[mi][nt] = (f32x4){0.f, 0.f, 0.f, 0.f};
        for (int nt = 0; nt < 2; ++nt)
            for (int kk = 0; kk < 4; ++kk) {
                bf16x8 kf = *(const bf16x8*)&smem[0][(wn * 32 + nt * 16 + l15) * KSTRIDE + kk * 32 + quad * 8];
                acc[0][nt] = __builtin_amdgcn_mfma_f32_16x16x32_bf16(qf[0][kk], kf, acc[0][nt], 0, 0, 0);
                acc[1][nt] = __builtin_amdgcn_mfma_f32_16x16x32_bf16(qf[1][kk], kf, acc[1][nt], 0, 0, 0);
            }

        // P: normalize, bf16 -> P_lds buffer, fp32 -> global attention
        unsigned short* pb = &smem[1][0] + (it & 1) * (TM * PSTRIDE);
        for (int mi = 0; mi < 2; ++mi)
            for (int nt = 0; nt < 2; ++nt)
                for (int r = 0; r < 4; ++r) {
                    float p = fexp2(acc[mi][nt][r] * SL2E) * inv[mi * 4 + r];
                    pb[(wm * 32 + mi * 16 + quad * 4 + r) * PSTRIDE + wn * 32 + nt * 16 + l15] = f2bf(p);
                    apb[(mi * 16 + r) * SS + k0 + nt * 16] = p;
                }
        __syncthreads();   // (a): P ready; K reads of this iter done

        // K stage for it+1 (overlapped with PV)
        bf16x8 g[4];
        if (it + 1 < NITER) {
            const unsigned short* kg = kgb + (size_t)((it + 1) * TN) * DD;
            for (int c = 0; c < 4; ++c)
                g[c] = *(const bf16x8*)(kg + c * 4096 + tid * 8);
        }

        // PV kk 0,1 (vf already in regs)
        for (int kk = 0; kk < 2; ++kk) {
            bf16x8 af[2];
            for (int mi = 0; mi < 2; ++mi)
                af[mi] = *(const bf16x8*)&pb[(wm * 32 + mi * 16 + l15) * PSTRIDE + kk * 32 + quad * 8];
            for (int ni = 0; ni < 2; ++ni)
                for (int mi = 0; mi < 2; ++mi)
                    cacc[mi][ni] = __builtin_amdgcn_mfma_f32_16x16x32_bf16(af[mi], vf[ni][kk], cacc[mi][ni], 0, 0, 0);
        }
        // V loads kk 2,3 then PV
        for (int ni = 0; ni < 2; ++ni)
            for (int kk = 0; kk < 2; ++kk)
                vf[ni][kk] = *(const bf16x8*)(vfb + ni * 16 * SS + k0 + (kk + 2) * 32);
        for (int kk = 0; kk < 2; ++kk) {
            bf16x8 af[2];
            for (int mi = 0; mi < 2; ++mi)
                af[mi] = *(const bf16x8*)&pb[(wm * 32 + mi * 16 + l15) * PSTRIDE + (kk + 2) * 32 + quad * 8];
            for (int ni = 0; ni < 2; ++ni)
                for (int mi = 0; mi < 2; ++mi)
                    cacc[mi][ni] = __builtin_amdgcn_mfma_f32_16x16x32_bf16(af[mi], vf[ni][kk], cacc[mi][ni], 0, 0, 0);
        }

        if (it + 1 < NITER) {
            for (int c = 0; c < 4; ++c) {
                int e = c * 4096 + tid * 8;
                *(bf16x8*)&smem[0][(e >> 7) * KSTRIDE + (e & 127)] = g[c];
            }
        }
        __syncthreads();   // (b): K tile it+1 staged; P buffer readers done
    }

    // epilogue: context
    float* cg = ctx + ((size_t)(bb * SS) + q0) * DD;
    for (int mi = 0; mi < 2; ++mi)
        for (int ni = 0; ni < 2; ++ni)
            for (int r = 0; r < 4; ++r) {
                int row = wm * 32 + mi * 16 + quad * 4 + r;
                int col = wn * 32 + ni * 16 + l15;
                cg[(size_t)row * DD + col] = cacc[mi][ni][r];
            }
}

extern "C" void kernel_launch(void* const* d_in, const int* in_sizes, int n_in,
                              void* d_out, int out_size, void* d_ws, size_t ws_size,
                              hipStream_t stream) {
    const float* q = (const float*)d_in[0];
    const float* k = (const float*)d_in[1];
    const float* v = (const float*)d_in[2];
    float* ctx = (float*)d_out;
    float* attn = ctx + (size_t)NB * SS * DD;

    unsigned short* kb = (unsigned short*)d_ws;            // B*S*D bf16
    unsigned short* vt = kb + (size_t)NB * SS * DD;        // [B][D][S] bf16

    prep_kernel<<<dim3(4, SS / 64, NB), 256, 0, stream>>>(k, v, kb, vt);
    attn_kernel<<<dim3((SS / TM) * NB), 512, 0, stream>>>(q, kb, vt, attn, ctx);
}